// Round 6
// baseline (409.942 us; speedup 1.0000x reference)
//
#include <hip/hip_runtime.h>
#include <stdint.h>

#define N_NODES 100000
#define E_EDGES 600000
#define IN_F    128
#define HID_F   256
#define OUT_F   128
#define NB_SCAN 98   // ceil(N_NODES / 1024)

typedef unsigned short ushort_t;
typedef short  short8  __attribute__((ext_vector_type(8)));
typedef float  floatx4 __attribute__((ext_vector_type(4)));

__device__ __forceinline__ float bf2f(unsigned u16) {
    return __uint_as_float(u16 << 16);
}
__device__ __forceinline__ ushort_t f2bf(float f) {
    unsigned u = __float_as_uint(f);
    return (ushort_t)((u + 0x7fffu + ((u >> 16) & 1u)) >> 16);   // RNE
}

// ---- fused prep: x fp32->bf16 cast + 4 weight transposes + cursor zeroing ---
__global__ void k_prep(const float* __restrict__ x, ushort_t* __restrict__ xbf,
                       const float* __restrict__ W1a, const float* __restrict__ W1b,
                       const float* __restrict__ W2a, const float* __restrict__ W2b,
                       ushort_t* __restrict__ WT1a, ushort_t* __restrict__ WT1b,
                       ushort_t* __restrict__ WT2a, ushort_t* __restrict__ WT2b,
                       int* __restrict__ cursor) {
    int t = blockIdx.x * 256 + threadIdx.x;
    if (t < N_NODES * IN_F / 2) {
        float2 v = ((const float2*)x)[t];
        ((unsigned*)xbf)[t] = (unsigned)f2bf(v.x) | ((unsigned)f2bf(v.y) << 16);
    }
    if (t < N_NODES) cursor[t] = 0;
    if (t < 32768) {
        int k = t >> 8, n = t & 255;
        WT1a[n * 128 + k] = f2bf(W1a[t]);
    } else if (t < 98304) {
        int i = t - 32768, k = i >> 8, n = i & 255;
        WT1b[n * 256 + k] = f2bf(W1b[i]);
    } else if (t < 163840) {
        int i = t - 98304, k = i >> 8, n = i & 255;
        WT2a[n * 256 + k] = f2bf(W2a[i]);
    } else if (t < 196608) {
        int i = t - 163840, k = i >> 7, n = i & 127;
        WT2b[n * 256 + k] = f2bf(W2b[i]);
    }
}

// ---------------- CSR build --------------------------------------------------
__global__ void k_hist(const int* __restrict__ dst, int* __restrict__ deg) {
    int e = blockIdx.x * 256 + threadIdx.x;
    if (e < E_EDGES) atomicAdd(&deg[dst[e]], 1);
}

__global__ void k_scan1(const int* __restrict__ deg, int* __restrict__ row_ptr,
                        int* __restrict__ psum) {
    __shared__ int s[1024];
    int t = threadIdx.x, i = blockIdx.x * 1024 + t;
    int v = (i < N_NODES) ? deg[i] : 0;
    s[t] = v;
    __syncthreads();
    for (int off = 1; off < 1024; off <<= 1) {
        int u = (t >= off) ? s[t - off] : 0;
        __syncthreads();
        if (t >= off) s[t] += u;
        __syncthreads();
    }
    if (i < N_NODES) row_ptr[i] = s[t] - v;          // exclusive within block
    if (t == 1023) psum[blockIdx.x] = s[t];          // block total
}

__global__ void k_scan2(int* __restrict__ psum) {
    __shared__ int s[128];
    int t = threadIdx.x;
    int v = (t < NB_SCAN) ? psum[t] : 0;
    s[t] = v;
    __syncthreads();
    for (int off = 1; off < 128; off <<= 1) {
        int u = (t >= off) ? s[t - off] : 0;
        __syncthreads();
        if (t >= off) s[t] += u;
        __syncthreads();
    }
    if (t < NB_SCAN) psum[t] = s[t] - v;             // exclusive block offsets
}

__global__ void k_scan3(int* __restrict__ row_ptr, const int* __restrict__ psum,
                        int* __restrict__ cursor) {
    int i = blockIdx.x * 1024 + threadIdx.x;
    if (i < N_NODES) {
        int r = row_ptr[i] + psum[i >> 10];
        row_ptr[i] = r;
        cursor[i]  = r;
    }
    if (i == 0) row_ptr[N_NODES] = E_EDGES;
}

__global__ void k_fill(const int* __restrict__ src, const int* __restrict__ dst,
                       int* __restrict__ cursor, int* __restrict__ colidx) {
    int e = blockIdx.x * 256 + threadIdx.x;
    if (e < E_EDGES) {
        int pos = atomicAdd(&cursor[dst[e]], 1);
        colidx[pos] = src[e];
    }
}

// ---- gather aggregation L1: Out[i] = xbf[i] + sum_j xbf[colidx[j]] (bf16, F=128)
// one wave/node, 2 bf16/lane; masked 8-wide gather batches (8 loads in flight)
__global__ void k_agg128(const ushort_t* __restrict__ Xbf, const int* __restrict__ row_ptr,
                         const int* __restrict__ colidx, ushort_t* __restrict__ Out) {
    int node = blockIdx.x * 4 + (threadIdx.x >> 6);
    int lane = threadIdx.x & 63;
    const unsigned* xr = (const unsigned*)Xbf;
    unsigned u = xr[node * 64 + lane];
    float a0 = bf2f(u & 0xffffu), a1 = bf2f(u >> 16);
    int r0 = row_ptr[node], r1 = row_ptr[node + 1];
    for (int rb = r0; rb < r1; rb += 8) {
        int   j[8];
        float m[8];
#pragma unroll
        for (int k = 0; k < 8; ++k) {
            int rr = rb + k;
            bool v = rr < r1;
            j[k] = v ? colidx[rr] : 0;     // clamp to node 0 (row stays hot in L1)
            m[k] = v ? 1.f : 0.f;
        }
        unsigned w[8];
#pragma unroll
        for (int k = 0; k < 8; ++k) w[k] = xr[j[k] * 64 + lane];
#pragma unroll
        for (int k = 0; k < 8; ++k) {
            a0 = fmaf(m[k], bf2f(w[k] & 0xffffu), a0);
            a1 = fmaf(m[k], bf2f(w[k] >> 16), a1);
        }
    }
    ((unsigned*)Out)[node * 64 + lane] =
        (unsigned)f2bf(a0) | ((unsigned)f2bf(a1) << 16);
}

// ---- gather aggregation L2: Out[i] = H[i] + sum_j H[colidx[j]]  (H bf16, F=256)
// one wave/node, 4 bf16/lane; masked 8-wide gather batches
__global__ void k_agg256(const ushort_t* __restrict__ X, const int* __restrict__ row_ptr,
                         const int* __restrict__ colidx, ushort_t* __restrict__ Out) {
    int node = blockIdx.x * 4 + (threadIdx.x >> 6);
    int lane = threadIdx.x & 63;
    const uint2* xr = (const uint2*)X;               // 4 bf16 per uint2
    uint2 u = xr[node * 64 + lane];
    float a0 = bf2f(u.x & 0xffffu), a1 = bf2f(u.x >> 16);
    float a2 = bf2f(u.y & 0xffffu), a3 = bf2f(u.y >> 16);
    int r0 = row_ptr[node], r1 = row_ptr[node + 1];
    for (int rb = r0; rb < r1; rb += 8) {
        int   j[8];
        float m[8];
#pragma unroll
        for (int k = 0; k < 8; ++k) {
            int rr = rb + k;
            bool v = rr < r1;
            j[k] = v ? colidx[rr] : 0;
            m[k] = v ? 1.f : 0.f;
        }
        uint2 w[8];
#pragma unroll
        for (int k = 0; k < 8; ++k) w[k] = xr[j[k] * 64 + lane];
#pragma unroll
        for (int k = 0; k < 8; ++k) {
            a0 = fmaf(m[k], bf2f(w[k].x & 0xffffu), a0);
            a1 = fmaf(m[k], bf2f(w[k].x >> 16), a1);
            a2 = fmaf(m[k], bf2f(w[k].y & 0xffffu), a2);
            a3 = fmaf(m[k], bf2f(w[k].y >> 16), a3);
        }
    }
    uint2 o;
    o.x = (unsigned)f2bf(a0) | ((unsigned)f2bf(a1) << 16);
    o.y = (unsigned)f2bf(a2) | ((unsigned)f2bf(a3) << 16);
    ((uint2*)Out)[node * 64 + lane] = o;
}

// ---------------- GEMM: Out = relu(Act[nRows x FIN] @ W + b) -----------------
// Act bf16, WT [FOUT][FIN] bf16, bias fp32. Block: 512 thr (8 waves),
// 256 rows x 128 cols. grid = (ceil(nRows/256), FOUT/128).
// LDS slab 128 cols x FIN (32/64 KB) -> 2 blocks/CU = 16 waves/CU.
template <int FIN, int FOUT, bool OUT_F32>
__global__ __launch_bounds__(512, 4) void gemm_relu(
    const ushort_t* __restrict__ Act, const ushort_t* __restrict__ WT,
    const float* __restrict__ bias, void* __restrict__ Out, int nRows)
{
    constexpr int CPR = FIN / 8;                  // 16B chunks per LDS row
    constexpr int KC  = FIN / 32;                 // k-chunks (4 or 8)
    constexpr int KH  = (KC > 4) ? 4 : KC;        // chunks per prefetch half
    __shared__ ushort_t wt[128 * FIN];

    const int tid  = threadIdx.x;
    const int slab = blockIdx.y * 128;

    // stage WT slab -> LDS; source addresses permuted so LDS holds the
    // xor-swizzled layout (chunk ^ (n & 15)) with fully coalesced loads
    {
        const ushort_t* wsrc = WT + (size_t)slab * FIN;
#pragma unroll
        for (int rr = 0; rr < (128 * CPR) / 512; ++rr) {
            int ci  = rr * 512 + tid;
            int n   = ci / CPR;
            int csw = ci % CPR;
            int cor = csw ^ (n & 15);
            uint4 v = *(const uint4*)(wsrc + (size_t)n * FIN + cor * 8);
            *(uint4*)&wt[ci * 8] = v;
        }
    }

    const int wave = tid >> 6, lane = tid & 63;
    const int quad = lane >> 4, l15 = lane & 15;
    const int rowBase = blockIdx.x * 256 + wave * 32;

    int r0 = rowBase + l15;
    int r1 = r0 + 16;
    r0 = (r0 < nRows) ? r0 : (nRows - 1);
    r1 = (r1 < nRows) ? r1 : (nRows - 1);
    const ushort_t* a0p = Act + (size_t)r0 * FIN + quad * 8;
    const ushort_t* a1p = Act + (size_t)r1 * FIN + quad * 8;

    // prefetch first half-K A-fragments (batched -> 8 loads in flight)
    short8 af[2][KH];
#pragma unroll
    for (int kc = 0; kc < KH; ++kc) {
        af[0][kc] = *(const short8*)(a0p + kc * 32);
        af[1][kc] = *(const short8*)(a1p + kc * 32);
    }

    floatx4 acc[2][8];
#pragma unroll
    for (int mt = 0; mt < 2; ++mt)
#pragma unroll
        for (int nt = 0; nt < 8; ++nt)
#pragma unroll
            for (int r = 0; r < 4; ++r) acc[mt][nt][r] = 0.f;

    __syncthreads();

#pragma unroll
    for (int half = 0; half < KC / KH; ++half) {
        if (half > 0) {
#pragma unroll
            for (int kc = 0; kc < KH; ++kc) {
                af[0][kc] = *(const short8*)(a0p + (KH + kc) * 32);
                af[1][kc] = *(const short8*)(a1p + (KH + kc) * 32);
            }
        }
#pragma unroll
        for (int kc = 0; kc < KH; ++kc) {
            int chunk = (half * KH + kc) * 4 + quad;
#pragma unroll
            for (int nt = 0; nt < 8; ++nt) {
                int n = nt * 16 + l15;
                int csw = chunk ^ (n & 15);
                short8 bfr = *(const short8*)&wt[n * FIN + csw * 8];
                acc[0][nt] = __builtin_amdgcn_mfma_f32_16x16x32_bf16(af[0][kc], bfr, acc[0][nt], 0, 0, 0);
                acc[1][nt] = __builtin_amdgcn_mfma_f32_16x16x32_bf16(af[1][kc], bfr, acc[1][nt], 0, 0, 0);
            }
        }
    }

    // epilogue: col = slab + nt*16 + l15, row = rowBase + mt*16 + quad*4 + r
#pragma unroll
    for (int mt = 0; mt < 2; ++mt) {
#pragma unroll
        for (int nt = 0; nt < 8; ++nt) {
            int col = slab + nt * 16 + l15;
            float bv = bias[col];
#pragma unroll
            for (int r = 0; r < 4; ++r) {
                int row = rowBase + mt * 16 + quad * 4 + r;
                if (row < nRows) {
                    float v = fmaxf(acc[mt][nt][r] + bv, 0.f);
                    if (OUT_F32)
                        ((float*)Out)[(size_t)row * FOUT + col] = v;
                    else
                        ((ushort_t*)Out)[(size_t)row * FOUT + col] = f2bf(v);
                }
            }
        }
    }
}

extern "C" void kernel_launch(void* const* d_in, const int* in_sizes, int n_in,
                              void* d_out, int out_size, void* d_ws, size_t ws_size,
                              hipStream_t stream) {
    const float* x   = (const float*)d_in[0];
    const int*   ei  = (const int*)d_in[1];
    const int*   src = ei;
    const int*   dst = ei + E_EDGES;
    const float* W1a = (const float*)d_in[2];
    const float* b1a = (const float*)d_in[3];
    const float* W1b = (const float*)d_in[4];
    const float* b1b = (const float*)d_in[5];
    const float* W2a = (const float*)d_in[6];
    const float* b2a = (const float*)d_in[7];
    const float* W2b = (const float*)d_in[8];
    const float* b2b = (const float*)d_in[9];

    // workspace layout (~106 MB)
    ushort_t* P       = (ushort_t*)d_ws;                       // N x 256 bf16
    ushort_t* Q       = P + (size_t)N_NODES * HID_F;           // N x 256 bf16
    ushort_t* xbf     = Q;   // x as bf16 (N x 128) — dead before Q is written
    int*      row_ptr = (int*)(Q + (size_t)N_NODES * HID_F);   // N+4 ints
    int*      cursor  = row_ptr + (N_NODES + 4);               // N ints
    int*      colidx  = cursor + N_NODES;                      // E ints
    int*      psum    = colidx + E_EDGES;                      // 128 ints
    ushort_t* WT1a    = (ushort_t*)(psum + 128);
    ushort_t* WT1b    = WT1a + 256 * 128;
    ushort_t* WT2a    = WT1b + 256 * 256;
    ushort_t* WT2b    = WT2a + 256 * 256;

    // fused x-cast + weight transpose + cursor zero
    k_prep<<<(N_NODES * IN_F / 2 + 255) / 256, 256, 0, stream>>>(
        x, xbf, W1a, W1b, W2a, W2b, WT1a, WT1b, WT2a, WT2b, cursor);

    // CSR build
    k_hist <<<(E_EDGES + 255) / 256, 256, 0, stream>>>(dst, cursor);
    k_scan1<<<NB_SCAN, 1024, 0, stream>>>(cursor, row_ptr, psum);
    k_scan2<<<1, 128, 0, stream>>>(psum);
    k_scan3<<<NB_SCAN, 1024, 0, stream>>>(row_ptr, psum, cursor);
    k_fill <<<(E_EDGES + 255) / 256, 256, 0, stream>>>(src, dst, cursor, colidx);

    const int ROWB = (N_NODES + 255) / 256;   // 391

    // layer 1: P := agg(xbf) [N x 128]; Q := relu(P@W1a+b1a); P := relu(Q@W1b+b1b) = h1
    k_agg128<<<N_NODES / 4, 256, 0, stream>>>(xbf, row_ptr, colidx, P);
    gemm_relu<128, 256, false><<<dim3(ROWB, 2), 512, 0, stream>>>(P, WT1a, b1a, Q, N_NODES);
    gemm_relu<256, 256, false><<<dim3(ROWB, 2), 512, 0, stream>>>(Q, WT1b, b1b, P, N_NODES);

    // layer 2: Q := agg(h1) [N x 256]; P := relu(Q@W2a+b2a); out := relu(P@W2b+b2b) fp32
    k_agg256<<<N_NODES / 4, 256, 0, stream>>>(P, row_ptr, colidx, Q);
    gemm_relu<256, 256, false><<<dim3(ROWB, 2), 512, 0, stream>>>(Q, WT2a, b2a, P, N_NODES);
    gemm_relu<256, 128, true><<<dim3(ROWB, 1), 512, 0, stream>>>(P, WT2b, b2b, d_out, N_NODES);
}

// Round 7
// 402.068 us; speedup vs baseline: 1.0196x; 1.0196x over previous
//
#include <hip/hip_runtime.h>
#include <stdint.h>

#define N_NODES 100000
#define E_EDGES 600000
#define IN_F    128
#define HID_F   256
#define OUT_F   128
#define NB_SCAN 98   // ceil(N_NODES / 1024)

typedef unsigned short ushort_t;
typedef short  short8  __attribute__((ext_vector_type(8)));
typedef float  floatx4 __attribute__((ext_vector_type(4)));

__device__ __forceinline__ float bf2f(unsigned u16) {
    return __uint_as_float(u16 << 16);
}
__device__ __forceinline__ ushort_t f2bf(float f) {
    unsigned u = __float_as_uint(f);
    return (ushort_t)((u + 0x7fffu + ((u >> 16) & 1u)) >> 16);   // RNE
}

// ---- fused prep: x fp32->bf16 cast + 4 weight transposes + cursor zeroing ---
__global__ void k_prep(const float* __restrict__ x, ushort_t* __restrict__ xbf,
                       const float* __restrict__ W1a, const float* __restrict__ W1b,
                       const float* __restrict__ W2a, const float* __restrict__ W2b,
                       ushort_t* __restrict__ WT1a, ushort_t* __restrict__ WT1b,
                       ushort_t* __restrict__ WT2a, ushort_t* __restrict__ WT2b,
                       int* __restrict__ cursor) {
    int t = blockIdx.x * 256 + threadIdx.x;
    if (t < N_NODES * IN_F / 2) {
        float2 v = ((const float2*)x)[t];
        ((unsigned*)xbf)[t] = (unsigned)f2bf(v.x) | ((unsigned)f2bf(v.y) << 16);
    }
    if (t < N_NODES) cursor[t] = 0;
    if (t < 32768) {
        int k = t >> 8, n = t & 255;
        WT1a[n * 128 + k] = f2bf(W1a[t]);
    } else if (t < 98304) {
        int i = t - 32768, k = i >> 8, n = i & 255;
        WT1b[n * 256 + k] = f2bf(W1b[i]);
    } else if (t < 163840) {
        int i = t - 98304, k = i >> 8, n = i & 255;
        WT2a[n * 256 + k] = f2bf(W2a[i]);
    } else if (t < 196608) {
        int i = t - 163840, k = i >> 7, n = i & 127;
        WT2b[n * 256 + k] = f2bf(W2b[i]);
    }
}

// ---------------- CSR build --------------------------------------------------
__global__ void k_hist(const int* __restrict__ dst, int* __restrict__ deg) {
    int e = blockIdx.x * 256 + threadIdx.x;
    if (e < E_EDGES) atomicAdd(&deg[dst[e]], 1);
}

__global__ void k_scan1(const int* __restrict__ deg, int* __restrict__ row_ptr,
                        int* __restrict__ psum) {
    __shared__ int s[1024];
    int t = threadIdx.x, i = blockIdx.x * 1024 + t;
    int v = (i < N_NODES) ? deg[i] : 0;
    s[t] = v;
    __syncthreads();
    for (int off = 1; off < 1024; off <<= 1) {
        int u = (t >= off) ? s[t - off] : 0;
        __syncthreads();
        if (t >= off) s[t] += u;
        __syncthreads();
    }
    if (i < N_NODES) row_ptr[i] = s[t] - v;          // exclusive within block
    if (t == 1023) psum[blockIdx.x] = s[t];          // block total
}

__global__ void k_scan2(int* __restrict__ psum) {
    __shared__ int s[128];
    int t = threadIdx.x;
    int v = (t < NB_SCAN) ? psum[t] : 0;
    s[t] = v;
    __syncthreads();
    for (int off = 1; off < 128; off <<= 1) {
        int u = (t >= off) ? s[t - off] : 0;
        __syncthreads();
        if (t >= off) s[t] += u;
        __syncthreads();
    }
    if (t < NB_SCAN) psum[t] = s[t] - v;             // exclusive block offsets
}

__global__ void k_scan3(int* __restrict__ row_ptr, const int* __restrict__ psum,
                        int* __restrict__ cursor) {
    int i = blockIdx.x * 1024 + threadIdx.x;
    if (i < N_NODES) {
        int r = row_ptr[i] + psum[i >> 10];
        row_ptr[i] = r;
        cursor[i]  = r;
    }
    if (i == 0) row_ptr[N_NODES] = E_EDGES;
}

__global__ void k_fill(const int* __restrict__ src, const int* __restrict__ dst,
                       int* __restrict__ cursor, int* __restrict__ colidx) {
    int e = blockIdx.x * 256 + threadIdx.x;
    if (e < E_EDGES) {
        int pos = atomicAdd(&cursor[dst[e]], 1);
        colidx[pos] = src[e];
    }
}

// ---- gather aggregation L1 (round-5 form): 4-deep unrolled gather -----------
__global__ void k_agg128(const ushort_t* __restrict__ Xbf, const int* __restrict__ row_ptr,
                         const int* __restrict__ colidx, ushort_t* __restrict__ Out) {
    int node = blockIdx.x * 4 + (threadIdx.x >> 6);
    int lane = threadIdx.x & 63;
    const unsigned* xr = (const unsigned*)Xbf;
    unsigned u = xr[node * 64 + lane];
    float a0 = bf2f(u & 0xffffu), a1 = bf2f(u >> 16);
    int r0 = row_ptr[node], r1 = row_ptr[node + 1];
    int r = r0;
    for (; r + 4 <= r1; r += 4) {
        int j0 = colidx[r], j1 = colidx[r + 1], j2 = colidx[r + 2], j3 = colidx[r + 3];
        unsigned w0 = xr[j0 * 64 + lane];
        unsigned w1 = xr[j1 * 64 + lane];
        unsigned w2 = xr[j2 * 64 + lane];
        unsigned w3 = xr[j3 * 64 + lane];
        a0 += (bf2f(w0 & 0xffffu) + bf2f(w1 & 0xffffu)) +
              (bf2f(w2 & 0xffffu) + bf2f(w3 & 0xffffu));
        a1 += (bf2f(w0 >> 16) + bf2f(w1 >> 16)) +
              (bf2f(w2 >> 16) + bf2f(w3 >> 16));
    }
    for (; r < r1; ++r) {
        int j = colidx[r];
        unsigned w = xr[j * 64 + lane];
        a0 += bf2f(w & 0xffffu);
        a1 += bf2f(w >> 16);
    }
    ((unsigned*)Out)[node * 64 + lane] =
        (unsigned)f2bf(a0) | ((unsigned)f2bf(a1) << 16);
}

// ---- gather aggregation L2 (round-5 form): 4-deep unrolled gather -----------
__global__ void k_agg256(const ushort_t* __restrict__ X, const int* __restrict__ row_ptr,
                         const int* __restrict__ colidx, ushort_t* __restrict__ Out) {
    int node = blockIdx.x * 4 + (threadIdx.x >> 6);
    int lane = threadIdx.x & 63;
    const uint2* xr = (const uint2*)X;               // 4 bf16 per uint2
    uint2 u = xr[node * 64 + lane];
    float a0 = bf2f(u.x & 0xffffu), a1 = bf2f(u.x >> 16);
    float a2 = bf2f(u.y & 0xffffu), a3 = bf2f(u.y >> 16);
    int r0 = row_ptr[node], r1 = row_ptr[node + 1];
    int r = r0;
    for (; r + 4 <= r1; r += 4) {
        int j0 = colidx[r], j1 = colidx[r + 1], j2 = colidx[r + 2], j3 = colidx[r + 3];
        uint2 w0 = xr[j0 * 64 + lane];
        uint2 w1 = xr[j1 * 64 + lane];
        uint2 w2 = xr[j2 * 64 + lane];
        uint2 w3 = xr[j3 * 64 + lane];
        a0 += (bf2f(w0.x & 0xffffu) + bf2f(w1.x & 0xffffu)) +
              (bf2f(w2.x & 0xffffu) + bf2f(w3.x & 0xffffu));
        a1 += (bf2f(w0.x >> 16) + bf2f(w1.x >> 16)) +
              (bf2f(w2.x >> 16) + bf2f(w3.x >> 16));
        a2 += (bf2f(w0.y & 0xffffu) + bf2f(w1.y & 0xffffu)) +
              (bf2f(w2.y & 0xffffu) + bf2f(w3.y & 0xffffu));
        a3 += (bf2f(w0.y >> 16) + bf2f(w1.y >> 16)) +
              (bf2f(w2.y >> 16) + bf2f(w3.y >> 16));
    }
    for (; r < r1; ++r) {
        int j = colidx[r];
        uint2 w = xr[j * 64 + lane];
        a0 += bf2f(w.x & 0xffffu); a1 += bf2f(w.x >> 16);
        a2 += bf2f(w.y & 0xffffu); a3 += bf2f(w.y >> 16);
    }
    uint2 o;
    o.x = (unsigned)f2bf(a0) | ((unsigned)f2bf(a1) << 16);
    o.y = (unsigned)f2bf(a2) | ((unsigned)f2bf(a3) << 16);
    ((uint2*)Out)[node * 64 + lane] = o;
}

// ---------------- GEMM: Out = relu(Act[nRows x FIN] @ W + b) -----------------
// Act bf16, WT [FOUT][FIN] bf16, bias fp32. Block: 512 thr (8 waves),
// 256 rows x 128 cols. grid = (ceil(nRows/256), FOUT/128).
// LDS slab 128 cols x FIN -> 2 blocks/CU = 16 waves/CU.
// WT staged via global_load_lds (width 16); A-fragments double-buffered in
// chunk-pairs so next pair's global loads overlap current pair's MFMAs.
template <int FIN, int FOUT, bool OUT_F32>
__global__ __launch_bounds__(512, 4) void gemm_relu(
    const ushort_t* __restrict__ Act, const ushort_t* __restrict__ WT,
    const float* __restrict__ bias, void* __restrict__ Out, int nRows)
{
    constexpr int CPR = FIN / 8;                  // 16B chunks per LDS row
    constexpr int KC  = FIN / 32;                 // k-chunks (4 or 8)
    constexpr int KP  = KC / 2;                   // chunk-pairs
    __shared__ ushort_t wt[128 * FIN];

    const int tid  = threadIdx.x;
    const int slab = blockIdx.y * 128;

    // stage WT slab -> LDS via async global_load_lds (16B/lane).
    // LDS dest per lane = ci*16B = wave-uniform base + lane*16 (required form).
    // Source chunk permuted (cor = csw ^ (n&15)) so LDS holds the swizzled layout.
    {
        const ushort_t* wsrc = WT + (size_t)slab * FIN;
#pragma unroll
        for (int rr = 0; rr < (128 * CPR) / 512; ++rr) {
            int ci  = rr * 512 + tid;
            int n   = ci / CPR;
            int csw = ci % CPR;
            int cor = csw ^ (n & 15);
            const ushort_t* g = wsrc + (size_t)n * FIN + cor * 8;
            __builtin_amdgcn_global_load_lds(
                (const __attribute__((address_space(1))) unsigned*)g,
                (__attribute__((address_space(3))) unsigned*)&wt[ci * 8],
                16, 0, 0);
        }
    }

    const int wave = tid >> 6, lane = tid & 63;
    const int quad = lane >> 4, l15 = lane & 15;
    const int rowBase = blockIdx.x * 256 + wave * 32;

    int r0 = rowBase + l15;
    int r1 = r0 + 16;
    r0 = (r0 < nRows) ? r0 : (nRows - 1);
    r1 = (r1 < nRows) ? r1 : (nRows - 1);
    const ushort_t* a0p = Act + (size_t)r0 * FIN + quad * 8;
    const ushort_t* a1p = Act + (size_t)r1 * FIN + quad * 8;

    // double-buffered A-fragments: [buf][m][kc], pair = 2 k-chunks
    short8 af[2][2][2];
#pragma unroll
    for (int kc = 0; kc < 2; ++kc) {
        af[0][0][kc] = *(const short8*)(a0p + kc * 32);
        af[0][1][kc] = *(const short8*)(a1p + kc * 32);
    }

    floatx4 acc[2][8];
#pragma unroll
    for (int mt = 0; mt < 2; ++mt)
#pragma unroll
        for (int nt = 0; nt < 8; ++nt)
#pragma unroll
            for (int r = 0; r < 4; ++r) acc[mt][nt][r] = 0.f;

    __syncthreads();   // drains global_load_lds (vmcnt) + all waves arrived

#pragma unroll
    for (int p = 0; p < KP; ++p) {
        const int cb = p & 1, nb = cb ^ 1;
        if (p + 1 < KP) {
#pragma unroll
            for (int kc = 0; kc < 2; ++kc) {
                af[nb][0][kc] = *(const short8*)(a0p + ((p + 1) * 2 + kc) * 32);
                af[nb][1][kc] = *(const short8*)(a1p + ((p + 1) * 2 + kc) * 32);
            }
        }
#pragma unroll
        for (int kc = 0; kc < 2; ++kc) {
            int chunk = (p * 2 + kc) * 4 + quad;
#pragma unroll
            for (int nt = 0; nt < 8; ++nt) {
                int n = nt * 16 + l15;
                int csw = chunk ^ (n & 15);
                short8 bfr = *(const short8*)&wt[n * FIN + csw * 8];
                acc[0][nt] = __builtin_amdgcn_mfma_f32_16x16x32_bf16(af[cb][0][kc], bfr, acc[0][nt], 0, 0, 0);
                acc[1][nt] = __builtin_amdgcn_mfma_f32_16x16x32_bf16(af[cb][1][kc], bfr, acc[1][nt], 0, 0, 0);
            }
        }
    }

    // epilogue: col = slab + nt*16 + l15, row = rowBase + mt*16 + quad*4 + r
#pragma unroll
    for (int mt = 0; mt < 2; ++mt) {
#pragma unroll
        for (int nt = 0; nt < 8; ++nt) {
            int col = slab + nt * 16 + l15;
            float bv = bias[col];
#pragma unroll
            for (int r = 0; r < 4; ++r) {
                int row = rowBase + mt * 16 + quad * 4 + r;
                if (row < nRows) {
                    float v = fmaxf(acc[mt][nt][r] + bv, 0.f);
                    if (OUT_F32)
                        ((float*)Out)[(size_t)row * FOUT + col] = v;
                    else
                        ((ushort_t*)Out)[(size_t)row * FOUT + col] = f2bf(v);
                }
            }
        }
    }
}

extern "C" void kernel_launch(void* const* d_in, const int* in_sizes, int n_in,
                              void* d_out, int out_size, void* d_ws, size_t ws_size,
                              hipStream_t stream) {
    const float* x   = (const float*)d_in[0];
    const int*   ei  = (const int*)d_in[1];
    const int*   src = ei;
    const int*   dst = ei + E_EDGES;
    const float* W1a = (const float*)d_in[2];
    const float* b1a = (const float*)d_in[3];
    const float* W1b = (const float*)d_in[4];
    const float* b1b = (const float*)d_in[5];
    const float* W2a = (const float*)d_in[6];
    const float* b2a = (const float*)d_in[7];
    const float* W2b = (const float*)d_in[8];
    const float* b2b = (const float*)d_in[9];

    // workspace layout (~106 MB)
    ushort_t* P       = (ushort_t*)d_ws;                       // N x 256 bf16
    ushort_t* Q       = P + (size_t)N_NODES * HID_F;           // N x 256 bf16
    ushort_t* xbf     = Q;   // x as bf16 (N x 128) — dead before Q is written
    int*      row_ptr = (int*)(Q + (size_t)N_NODES * HID_F);   // N+4 ints
    int*      cursor  = row_ptr + (N_NODES + 4);               // N ints
    int*      colidx  = cursor + N_NODES;                      // E ints
    int*      psum    = colidx + E_EDGES;                      // 128 ints
    ushort_t* WT1a    = (ushort_t*)(psum + 128);
    ushort_t* WT1b    = WT1a + 256 * 128;
    ushort_t* WT2a    = WT1b + 256 * 256;
    ushort_t* WT2b    = WT2a + 256 * 256;

    // fused x-cast + weight transpose + cursor zero
    k_prep<<<(N_NODES * IN_F / 2 + 255) / 256, 256, 0, stream>>>(
        x, xbf, W1a, W1b, W2a, W2b, WT1a, WT1b, WT2a, WT2b, cursor);

    // CSR build
    k_hist <<<(E_EDGES + 255) / 256, 256, 0, stream>>>(dst, cursor);
    k_scan1<<<NB_SCAN, 1024, 0, stream>>>(cursor, row_ptr, psum);
    k_scan2<<<1, 128, 0, stream>>>(psum);
    k_scan3<<<NB_SCAN, 1024, 0, stream>>>(row_ptr, psum, cursor);
    k_fill <<<(E_EDGES + 255) / 256, 256, 0, stream>>>(src, dst, cursor, colidx);

    const int ROWB = (N_NODES + 255) / 256;   // 391

    // layer 1: P := agg(xbf) [N x 128]; Q := relu(P@W1a+b1a); P := relu(Q@W1b+b1b) = h1
    k_agg128<<<N_NODES / 4, 256, 0, stream>>>(xbf, row_ptr, colidx, P);
    gemm_relu<128, 256, false><<<dim3(ROWB, 2), 512, 0, stream>>>(P, WT1a, b1a, Q, N_NODES);
    gemm_relu<256, 256, false><<<dim3(ROWB, 2), 512, 0, stream>>>(Q, WT1b, b1b, P, N_NODES);

    // layer 2: Q := agg(h1) [N x 256]; P := relu(Q@W2a+b2a); out := relu(P@W2b+b2b) fp32
    k_agg256<<<N_NODES / 4, 256, 0, stream>>>(P, row_ptr, colidx, Q);
    gemm_relu<256, 256, false><<<dim3(ROWB, 2), 512, 0, stream>>>(Q, WT2a, b2a, P, N_NODES);
    gemm_relu<256, 128, true><<<dim3(ROWB, 1), 512, 0, stream>>>(P, WT2b, b2b, d_out, N_NODES);
}